// Round 8
// baseline (196.821 us; speedup 1.0000x reference)
//
#include <hip/hip_runtime.h>
#include <math.h>

#define NPTS 2048
#define BATCH 16
#define KNN 16
#define HID 128
#define RPB 8          // rows (queries) per block = waves per block
#define CAP 128        // compacted-candidate capacity per wave

typedef __attribute__((ext_vector_type(8))) short bf16x8;
typedef __attribute__((ext_vector_type(4))) float f32x4;

__device__ inline unsigned short f2bf(float f) {    // RNE f32 -> bf16 bits
    unsigned u = __float_as_uint(f);
    return (unsigned short)((u + 0x7FFFu + ((u >> 16) & 1u)) >> 16);
}
__device__ inline float bflo(unsigned v) { return __uint_as_float(v << 16); }
__device__ inline float bfhi(unsigned v) { return __uint_as_float(v & 0xFFFF0000u); }

// ---------------------------------------------------------------------------
// kNN + fused layer 1. One wave per query row.
// key = float_bits(d2 + 16) (monotone). Set-selection (neighbor order is
// irrelevant downstream — only summed); exact set via lex rank on (key,idx).
// Compaction via LDS atomics (nondeterministic order, deterministic set).
// Tail: wave-reduce neighbor position sum, then compute the 3->128 layer-1
// row (relu(W1r@agg + W1s@xi + b1)) directly -> x1 (bf16).
// ---------------------------------------------------------------------------
__global__ __launch_bounds__(512) void knn_kernel(
    const float* __restrict__ pc, int* __restrict__ nbr,
    const float* __restrict__ W1r, const float* __restrict__ b1,
    const float* __restrict__ W1s, unsigned short* __restrict__ x1)
{
    __shared__ __align__(16) float4 pts[NPTS];        // x,y,z,|p|^2  (32 KB)
    __shared__ uint2 cand[RPB][CAP];                  // 8 KB
    __shared__ unsigned ccnt[RPB];

    const int b = blockIdx.x >> 8;                    // 256 blocks per batch
    const int rblk = blockIdx.x & 255;
    const float* p = pc + (size_t)b * NPTS * 3;

    for (int t = threadIdx.x; t < NPTS; t += 512) {
        float x = p[t * 3 + 0], y = p[t * 3 + 1], z = p[t * 3 + 2];
        pts[t] = make_float4(x, y, z, x * x + y * y + z * z);
    }
    __syncthreads();

    const int w = threadIdx.x >> 6;
    const int lane = threadIdx.x & 63;
    const int i = rblk * RPB + w;                     // query row in batch
    const float4 pi = pts[i];
    const float piw16 = pi.w + 16.0f;

    if (lane == 0) ccnt[w] = 0;
    __threadfence_block();

    // ---- phase 1: 32 candidate keys per lane + running lane-min -----------
    unsigned key[32];
    unsigned km = 0xFFFFFFFFu;
    #pragma unroll
    for (int t = 0; t < 32; ++t) {
        float4 c = pts[t * 64 + lane];
        float dot = fmaf(pi.x, c.x, fmaf(pi.y, c.y, pi.z * c.z));
        float d2 = fmaf(-2.0f, dot, piw16 + c.w);
        key[t] = __float_as_uint(d2);
        km = min(km, key[t]);
    }

    // ---- phase 2: bitonic sort of 64 lane-mins; T0 = 16th smallest --------
    unsigned v = km;
    #pragma unroll
    for (int k = 2; k <= 64; k <<= 1) {
        #pragma unroll
        for (int j = k >> 1; j > 0; j >>= 1) {
            unsigned o = (unsigned)__shfl_xor((int)v, j, 64);
            bool sel = ((lane & k) == 0) == ((lane & j) == 0);
            v = sel ? min(v, o) : max(v, o);
        }
    }
    const unsigned T0 = (unsigned)__shfl((int)v, 15, 64);
    // >=16 candidates have key <= T0 (the 16 smallest lane-mins each cover
    // one), and T0 >= true 16th-smallest => {key <= T0} superset of top-16.

    // ---- phase 3: atomic compaction of survivors --------------------------
    #pragma unroll 1
    for (int t = 0; t < 32; ++t) {
        if (key[t] <= T0) {
            unsigned pos = atomicAdd(&ccnt[w], 1u);
            if (pos < CAP)
                cand[w][pos] = make_uint2(key[t], (unsigned)(t * 64 + lane));
        }
    }
    __threadfence_block();
    const int m = (int)ccnt[w];

    int* out = nbr + ((size_t)b * NPTS + i) * KNN;
    float ax = 0.f, ay = 0.f, az = 0.f;               // fused position sum

    if (m <= CAP) {
        // ---- phase 4: lex rank over survivors; rank<16 -> output ----------
        uint2 e0 = (lane < m) ? cand[w][lane] : make_uint2(0xFFFFFFFFu, 0xFFFFFFFFu);
        int r0 = 0;
        if (m <= 64) {
            #pragma unroll 1
            for (int jj = 0; jj < m; ++jj) {
                uint2 cj = cand[w][jj];
                r0 += (cj.x < e0.x) || (cj.x == e0.x && cj.y < e0.y);
            }
        } else {
            uint2 e1 = (lane + 64 < m) ? cand[w][lane + 64]
                                       : make_uint2(0xFFFFFFFFu, 0xFFFFFFFFu);
            int r1 = 0;
            #pragma unroll 1
            for (int jj = 0; jj < m; ++jj) {
                uint2 cj = cand[w][jj];
                r0 += (cj.x < e0.x) || (cj.x == e0.x && cj.y < e0.y);
                r1 += (cj.x < e1.x) || (cj.x == e1.x && cj.y < e1.y);
            }
            if (lane + 64 < m && r1 < KNN) {
                out[r1] = (int)e1.y;
                float4 q = pts[e1.y]; ax += q.x; ay += q.y; az += q.z;
            }
        }
        if (lane < m && r0 < KNN) {
            out[r0] = (int)e0.y;
            float4 q = pts[e0.y]; ax += q.x; ay += q.y; az += q.z;
        }
    } else {
        // exact fallback (never taken w/ random data; correctness only)
        unsigned T = 0;
        #pragma unroll 1
        for (int bit = 31; bit >= 0; --bit) {
            unsigned trial = T | (1u << bit);
            int cnt = 0;
            #pragma unroll
            for (int t = 0; t < 32; ++t) cnt += (key[t] < trial);
            #pragma unroll
            for (int off = 32; off; off >>= 1)
                cnt += __shfl_xor(cnt, off, 64);
            if (cnt < KNN) T = trial;
        }
        unsigned bs = 0;
        #pragma unroll 1
        for (int t = 0; t < 32; ++t) {
            bool p1 = key[t] < T;
            unsigned long long mask = __ballot(p1);
            if (mask) {
                unsigned prefix = __builtin_amdgcn_mbcnt_hi(
                    (unsigned)(mask >> 32),
                    __builtin_amdgcn_mbcnt_lo((unsigned)mask, 0));
                if (p1) {
                    out[bs + prefix] = t * 64 + lane;
                    float4 q = pts[t * 64 + lane];
                    ax += q.x; ay += q.y; az += q.z;
                }
                bs += (unsigned)__popcll(mask);
            }
        }
        #pragma unroll 1
        for (int t = 0; t < 32 && bs < KNN; ++t) {
            bool p2 = key[t] == T;
            unsigned long long mask = __ballot(p2);
            if (mask) {
                unsigned prefix = __builtin_amdgcn_mbcnt_hi(
                    (unsigned)(mask >> 32),
                    __builtin_amdgcn_mbcnt_lo((unsigned)mask, 0));
                unsigned pos = bs + prefix;
                if (p2 && pos < KNN) {
                    out[pos] = t * 64 + lane;
                    float4 q = pts[t * 64 + lane];
                    ax += q.x; ay += q.y; az += q.z;
                }
                bs += (unsigned)__popcll(mask);
            }
        }
    }

    // ---- wave-reduce position sums ----------------------------------------
    #pragma unroll
    for (int off = 32; off; off >>= 1) {
        ax += __shfl_xor(ax, off, 64);
        ay += __shfl_xor(ay, off, 64);
        az += __shfl_xor(az, off, 64);
    }

    // ---- fused layer 1: 3 -> 128, relu, bf16 ------------------------------
    unsigned short* xrow = x1 + ((size_t)b * NPTS + i) * HID;
    #pragma unroll
    for (int hh = 0; hh < 2; ++hh) {
        int h = lane + hh * 64;
        float acc = b1[h];
        acc += W1r[h * 3 + 0] * ax + W1r[h * 3 + 1] * ay + W1r[h * 3 + 2] * az;
        acc += W1s[h * 3 + 0] * pi.x + W1s[h * 3 + 1] * pi.y + W1s[h * 3 + 2] * pi.z;
        xrow[h] = f2bf(fmaxf(acc, 0.f));
    }
}

// ---------------------------------------------------------------------------
// Weight conversion: 4 x [128x128] f32 -> bf16.
// ---------------------------------------------------------------------------
__global__ __launch_bounds__(256) void wcvt_kernel(
    const float* __restrict__ a, const float* __restrict__ b,
    const float* __restrict__ c, const float* __restrict__ d,
    unsigned short* __restrict__ out)
{
    int g = blockIdx.x * 256 + threadIdx.x;       // < 65536
    int m = g >> 14;
    const float* s = (m == 0) ? a : (m == 1) ? b : (m == 2) ? c : d;
    out[g] = f2bf(s[g & 16383]);
}

// ---------------------------------------------------------------------------
// Fused gather + GraphConv via bf16 MFMA. (Unchanged from R7.)
// Block 512 thr = 8 waves, tile 64 points x 128 h.
// Gather: wave = 4 points x 16 chunks -> 256 B contiguous per row read.
// MFMA: wave (32 pt x 32 h); A from LDS/global, B=W rows from global (L1).
// Layouts [measured m89/m91]: A[m=lane&15][k=quad*8+j]; B^T same;
// D: col=lane&15, row=quad*4+reg.
// ---------------------------------------------------------------------------
template <bool RELU, bool OUT_BF16>
__global__ __launch_bounds__(512) void conv_fused(
    const unsigned short* __restrict__ x, const int* __restrict__ nbr,
    const unsigned short* __restrict__ Wr, const unsigned short* __restrict__ Ws,
    const float* __restrict__ bias, void* __restrict__ outv)
{
    __shared__ __align__(16) unsigned short aggs[64][136];   // 17.4 KB
    __shared__ int nbrs[64][17];                             // 4.4 KB
    const int p0 = blockIdx.x * 64;                          // global point base
    const int bt = p0 >> 11;                                 // batch
    const unsigned short* xb = x + ((size_t)bt << 11) * HID; // batch-local rows

    for (int e = threadIdx.x; e < 64 * KNN; e += 512)
        nbrs[e >> 4][e & 15] = nbr[(size_t)p0 * KNN + e];
    __syncthreads();

    #pragma unroll
    for (int it = 0; it < 2; ++it) {
        int task = it * 512 + threadIdx.x;        // 0..1023
        int c8 = task & 15, pt = task >> 4;       // pt 0..63
        const unsigned short* base = xb + c8 * 8;
        float s[8] = {0, 0, 0, 0, 0, 0, 0, 0};
        #pragma unroll
        for (int t = 0; t < KNN; ++t) {
            int j = nbrs[pt][t];
            uint4 v = *(const uint4*)(base + (size_t)j * HID);
            s[0] += bflo(v.x); s[1] += bfhi(v.x);
            s[2] += bflo(v.y); s[3] += bfhi(v.y);
            s[4] += bflo(v.z); s[5] += bfhi(v.z);
            s[6] += bflo(v.w); s[7] += bfhi(v.w);
        }
        uint4 ov;
        ov.x = (unsigned)f2bf(s[0]) | ((unsigned)f2bf(s[1]) << 16);
        ov.y = (unsigned)f2bf(s[2]) | ((unsigned)f2bf(s[3]) << 16);
        ov.z = (unsigned)f2bf(s[4]) | ((unsigned)f2bf(s[5]) << 16);
        ov.w = (unsigned)f2bf(s[6]) | ((unsigned)f2bf(s[7]) << 16);
        *(uint4*)&aggs[pt][c8 * 8] = ov;
    }
    __syncthreads();

    const int wv = threadIdx.x >> 6;
    const int lane = threadIdx.x & 63;
    const int ptw = (wv & 1) * 32;                // 0 / 32
    const int h0w = (wv >> 1) * 32;               // 0 / 32 / 64 / 96
    const int row = lane & 15;
    const int quad = lane >> 4;

    f32x4 acc[2][2];
    #pragma unroll
    for (int i = 0; i < 2; ++i)
        #pragma unroll
        for (int n = 0; n < 2; ++n) acc[i][n] = (f32x4){0, 0, 0, 0};

    #pragma unroll
    for (int kc = 0; kc < 4; ++kc) {
        bf16x8 a0 = *(const bf16x8*)&aggs[ptw + row][quad * 8 + kc * 32];
        bf16x8 a1 = *(const bf16x8*)&aggs[ptw + 16 + row][quad * 8 + kc * 32];
        #pragma unroll
        for (int n = 0; n < 2; ++n) {
            bf16x8 bb = *(const bf16x8*)&Wr[(size_t)(h0w + n * 16 + row) * HID
                                            + quad * 8 + kc * 32];
            acc[0][n] = __builtin_amdgcn_mfma_f32_16x16x32_bf16(a0, bb, acc[0][n], 0, 0, 0);
            acc[1][n] = __builtin_amdgcn_mfma_f32_16x16x32_bf16(a1, bb, acc[1][n], 0, 0, 0);
        }
    }
    const unsigned short* xr0 = x + (size_t)(p0 + ptw + row) * HID + quad * 8;
    const unsigned short* xr1 = xr0 + 16 * HID;
    #pragma unroll
    for (int kc = 0; kc < 4; ++kc) {
        bf16x8 a0 = *(const bf16x8*)(xr0 + kc * 32);
        bf16x8 a1 = *(const bf16x8*)(xr1 + kc * 32);
        #pragma unroll
        for (int n = 0; n < 2; ++n) {
            bf16x8 bb = *(const bf16x8*)&Ws[(size_t)(h0w + n * 16 + row) * HID
                                            + quad * 8 + kc * 32];
            acc[0][n] = __builtin_amdgcn_mfma_f32_16x16x32_bf16(a0, bb, acc[0][n], 0, 0, 0);
            acc[1][n] = __builtin_amdgcn_mfma_f32_16x16x32_bf16(a1, bb, acc[1][n], 0, 0, 0);
        }
    }

    #pragma unroll
    for (int n = 0; n < 2; ++n) {
        float bh = bias[h0w + n * 16 + row];
        #pragma unroll
        for (int i = 0; i < 2; ++i) {
            #pragma unroll
            for (int r = 0; r < 4; ++r) {
                int pp = p0 + ptw + i * 16 + quad * 4 + r;
                float vv = acc[i][n][r] + bh;
                if (RELU) vv = fmaxf(vv, 0.f);
                if (OUT_BF16)
                    ((unsigned short*)outv)[(size_t)pp * HID + h0w + n * 16 + row] = f2bf(vv);
                else
                    ((float*)outv)[(size_t)pp * HID + h0w + n * 16 + row] = vv;
            }
        }
    }
}

// ---------------------------------------------------------------------------
extern "C" void kernel_launch(void* const* d_in, const int* in_sizes, int n_in,
                              void* d_out, int out_size, void* d_ws, size_t ws_size,
                              hipStream_t stream)
{
    const float* pc  = (const float*)d_in[0];
    const float* W1r = (const float*)d_in[1];
    const float* b1  = (const float*)d_in[2];
    const float* W1s = (const float*)d_in[3];
    const float* W2r = (const float*)d_in[4];
    const float* b2  = (const float*)d_in[5];
    const float* W2s = (const float*)d_in[6];
    const float* W3r = (const float*)d_in[7];
    const float* b3  = (const float*)d_in[8];
    const float* W3s = (const float*)d_in[9];
    float* out = (float*)d_out;

    char* ws = (char*)d_ws;
    const size_t MB = 1024 * 1024;
    int*            nbr = (int*)ws;                             // 2 MB
    unsigned short* x1  = (unsigned short*)(ws + 2 * MB);       // 8.39 MB
    unsigned short* x2  = (unsigned short*)(ws + 2 * MB + 8388608);
    unsigned short* wbf = (unsigned short*)(ws + 2 * MB + 2 * 8388608);
    unsigned short* w2r = wbf;
    unsigned short* w2s = wbf + 16384;
    unsigned short* w3r = wbf + 32768;
    unsigned short* w3s = wbf + 49152;

    const int NPOINTS = BATCH * NPTS;                           // 32768

    wcvt_kernel<<<256, 256, 0, stream>>>(W2r, W2s, W3r, W3s, wbf);
    knn_kernel<<<NPOINTS / RPB, 512, 0, stream>>>(pc, nbr, W1r, b1, W1s, x1);

    conv_fused<true, true><<<NPOINTS / 64, 512, 0, stream>>>(
        x1, nbr, w2r, w2s, b2, x2);
    conv_fused<false, false><<<NPOINTS / 64, 512, 0, stream>>>(
        x2, nbr, w3r, w3s, b3, out);
}

// Round 9
// 185.096 us; speedup vs baseline: 1.0633x; 1.0633x over previous
//
#include <hip/hip_runtime.h>
#include <math.h>

#define NPTS 2048
#define BATCH 16
#define KNN 16
#define HID 128
#define RPB 8          // rows (queries) per block = waves per block
#define CAP 128        // compacted-candidate capacity per wave

typedef __attribute__((ext_vector_type(8))) short bf16x8;
typedef __attribute__((ext_vector_type(4))) float f32x4;

__device__ inline unsigned short f2bf(float f) {    // RNE f32 -> bf16 bits
    unsigned u = __float_as_uint(f);
    return (unsigned short)((u + 0x7FFFu + ((u >> 16) & 1u)) >> 16);
}
__device__ inline float bflo(unsigned v) { return __uint_as_float(v << 16); }
__device__ inline float bfhi(unsigned v) { return __uint_as_float(v & 0xFFFF0000u); }

// ---------------------------------------------------------------------------
// kNN + fused layer 1. One wave per query row. R7-proven ballot compaction
// (LDS atomics regressed: serialized same-address adds, 155K conflicts — R8).
// key = float_bits(d2 + 16) (monotone). Set-selection (neighbor order is
// irrelevant downstream — only summed); exact set via lex rank on (key,idx).
// Tail: wave-reduce neighbor position sum, compute relu(W1r@agg+W1s@xi+b1).
// ---------------------------------------------------------------------------
__global__ __launch_bounds__(512) void knn_kernel(
    const float* __restrict__ pc, int* __restrict__ nbr,
    const float* __restrict__ W1r, const float* __restrict__ b1,
    const float* __restrict__ W1s, unsigned short* __restrict__ x1)
{
    __shared__ __align__(16) float4 pts[NPTS];        // x,y,z,|p|^2  (32 KB)
    __shared__ unsigned ckey[RPB][CAP];               // 4 KB
    __shared__ unsigned cidx[RPB][CAP];               // 4 KB

    const int b = blockIdx.x >> 8;                    // 256 blocks per batch
    const int rblk = blockIdx.x & 255;
    const float* p = pc + (size_t)b * NPTS * 3;

    for (int t = threadIdx.x; t < NPTS; t += 512) {
        float x = p[t * 3 + 0], y = p[t * 3 + 1], z = p[t * 3 + 2];
        pts[t] = make_float4(x, y, z, x * x + y * y + z * z);
    }
    __syncthreads();

    const int w = threadIdx.x >> 6;
    const int lane = threadIdx.x & 63;
    const int i = rblk * RPB + w;                     // query row in batch
    const float4 pi = pts[i];
    const float piw16 = pi.w + 16.0f;

    unsigned key[32];
    unsigned km = 0xFFFFFFFFu;
    #pragma unroll
    for (int t = 0; t < 32; ++t) {
        float4 c = pts[t * 64 + lane];
        float dot = fmaf(pi.x, c.x, fmaf(pi.y, c.y, pi.z * c.z));
        float d2 = fmaf(-2.0f, dot, piw16 + c.w);
        key[t] = __float_as_uint(d2);
        km = min(km, key[t]);
    }

    unsigned v = km;
    #pragma unroll
    for (int k = 2; k <= 64; k <<= 1) {
        #pragma unroll
        for (int j = k >> 1; j > 0; j >>= 1) {
            unsigned o = (unsigned)__shfl_xor((int)v, j, 64);
            bool sel = ((lane & k) == 0) == ((lane & j) == 0);
            v = sel ? min(v, o) : max(v, o);
        }
    }
    const unsigned T0 = (unsigned)__shfl((int)v, 15, 64);
    // >=16 candidates have key <= T0, and T0 >= true 16th-smallest
    // => {key <= T0} is a superset of the top-16.

    unsigned base = 0;
    #pragma unroll 1
    for (int t = 0; t < 32; ++t) {
        bool pred = key[t] <= T0;
        unsigned long long mask = __ballot(pred);
        if (mask) {
            unsigned prefix = __builtin_amdgcn_mbcnt_hi(
                (unsigned)(mask >> 32),
                __builtin_amdgcn_mbcnt_lo((unsigned)mask, 0));
            unsigned pos = base + prefix;
            if (pred && pos < CAP) {
                ckey[w][pos] = key[t];
                cidx[w][pos] = (unsigned)(t * 64 + lane);
            }
            base += (unsigned)__popcll(mask);
        }
    }
    __threadfence_block();
    const int m = (int)base;

    int* out = nbr + ((size_t)b * NPTS + i) * KNN;
    float ax = 0.f, ay = 0.f, az = 0.f;               // fused position sum

    if (m <= CAP) {
        unsigned k0 = (lane < m) ? ckey[w][lane] : 0xFFFFFFFFu;
        unsigned k1 = (lane + 64 < m) ? ckey[w][lane + 64] : 0xFFFFFFFFu;
        int r0 = 0, r1 = 0;
        if (m <= 64) {
            #pragma unroll 1
            for (int jj = 0; jj < m; ++jj) {
                unsigned kj = ckey[w][jj];
                r0 += (kj < k0) || (kj == k0 && jj < lane);
            }
        } else {
            #pragma unroll 1
            for (int jj = 0; jj < m; ++jj) {
                unsigned kj = ckey[w][jj];
                r0 += (kj < k0) || (kj == k0 && jj < lane);
                r1 += (kj < k1) || (kj == k1 && jj < lane + 64);
            }
        }
        if (lane < m && r0 < KNN) {
            unsigned j = cidx[w][lane];
            out[r0] = (int)j;
            float4 q = pts[j]; ax += q.x; ay += q.y; az += q.z;
        }
        if (m > 64 && lane + 64 < m && r1 < KNN) {
            unsigned j = cidx[w][lane + 64];
            out[r1] = (int)j;
            float4 q = pts[j]; ax += q.x; ay += q.y; az += q.z;
        }
    } else {
        // exact fallback (never taken w/ random data; correctness only)
        unsigned T = 0;
        #pragma unroll 1
        for (int bit = 31; bit >= 0; --bit) {
            unsigned trial = T | (1u << bit);
            int cnt = 0;
            #pragma unroll
            for (int t = 0; t < 32; ++t) cnt += (key[t] < trial);
            #pragma unroll
            for (int off = 32; off; off >>= 1)
                cnt += __shfl_xor(cnt, off, 64);
            if (cnt < KNN) T = trial;
        }
        unsigned bs = 0;
        #pragma unroll 1
        for (int t = 0; t < 32; ++t) {
            bool p1 = key[t] < T;
            unsigned long long mask = __ballot(p1);
            if (mask) {
                unsigned prefix = __builtin_amdgcn_mbcnt_hi(
                    (unsigned)(mask >> 32),
                    __builtin_amdgcn_mbcnt_lo((unsigned)mask, 0));
                if (p1) {
                    out[bs + prefix] = t * 64 + lane;
                    float4 q = pts[t * 64 + lane];
                    ax += q.x; ay += q.y; az += q.z;
                }
                bs += (unsigned)__popcll(mask);
            }
        }
        #pragma unroll 1
        for (int t = 0; t < 32 && bs < KNN; ++t) {
            bool p2 = key[t] == T;
            unsigned long long mask = __ballot(p2);
            if (mask) {
                unsigned prefix = __builtin_amdgcn_mbcnt_hi(
                    (unsigned)(mask >> 32),
                    __builtin_amdgcn_mbcnt_lo((unsigned)mask, 0));
                unsigned pos = bs + prefix;
                if (p2 && pos < KNN) {
                    out[pos] = t * 64 + lane;
                    float4 q = pts[t * 64 + lane];
                    ax += q.x; ay += q.y; az += q.z;
                }
                bs += (unsigned)__popcll(mask);
            }
        }
    }

    // ---- wave-reduce position sums ----------------------------------------
    #pragma unroll
    for (int off = 32; off; off >>= 1) {
        ax += __shfl_xor(ax, off, 64);
        ay += __shfl_xor(ay, off, 64);
        az += __shfl_xor(az, off, 64);
    }

    // ---- fused layer 1: 3 -> 128, relu, bf16 ------------------------------
    unsigned short* xrow = x1 + ((size_t)b * NPTS + i) * HID;
    #pragma unroll
    for (int hh = 0; hh < 2; ++hh) {
        int h = lane + hh * 64;
        float acc = b1[h];
        acc += W1r[h * 3 + 0] * ax + W1r[h * 3 + 1] * ay + W1r[h * 3 + 2] * az;
        acc += W1s[h * 3 + 0] * pi.x + W1s[h * 3 + 1] * pi.y + W1s[h * 3 + 2] * pi.z;
        xrow[h] = f2bf(fmaxf(acc, 0.f));
    }
}

// ---------------------------------------------------------------------------
// Weight conversion: 4 x [128x128] f32 -> bf16.
// ---------------------------------------------------------------------------
__global__ __launch_bounds__(256) void wcvt_kernel(
    const float* __restrict__ a, const float* __restrict__ b,
    const float* __restrict__ c, const float* __restrict__ d,
    unsigned short* __restrict__ out)
{
    int g = blockIdx.x * 256 + threadIdx.x;       // < 65536
    int m = g >> 14;
    const float* s = (m == 0) ? a : (m == 1) ? b : (m == 2) ? c : d;
    out[g] = f2bf(s[g & 16383]);
}

// ---------------------------------------------------------------------------
// Fused gather + GraphConv via bf16 MFMA, v2: 1024-thread blocks.
// Tile 64 points x 128 h, 16 waves; grid 512 -> 2 blocks/CU = 32 waves/CU
// (100% occupancy; the gather is latency-bound so MLP is the lever —
// R7's 8-wave blocks capped at 16 waves/CU). 1 gather task/thread:
// (pt, c8), 16 independent 16B loads (256 B contiguous per row across
// 16 lanes). MFMA wave tile 16 pt x 32 h.
// Layouts [measured m89/m91]: A[m=lane&15][k=quad*8+j]; B^T same;
// D: col(lane&15)=h, row(quad*4+reg)=point.
// ---------------------------------------------------------------------------
template <bool RELU, bool OUT_BF16>
__global__ __launch_bounds__(1024, 8) void conv_fused(
    const unsigned short* __restrict__ x, const int* __restrict__ nbr,
    const unsigned short* __restrict__ Wr, const unsigned short* __restrict__ Ws,
    const float* __restrict__ bias, void* __restrict__ outv)
{
    __shared__ __align__(16) unsigned short aggs[64][136];   // 17.4 KB
    __shared__ int nbrs[64][17];                             // 4.4 KB
    const int p0 = blockIdx.x * 64;                          // global point base
    const int bt = p0 >> 11;                                 // batch
    const unsigned short* xb = x + ((size_t)bt << 11) * HID; // batch-local rows

    // ---- stage nbr into LDS (1 int/thread, coalesced) ---------------------
    {
        int e = threadIdx.x;                      // 0..1023 == 64*16
        nbrs[e >> 4][e & 15] = nbr[(size_t)p0 * KNN + e];
    }
    __syncthreads();

    // ---- gather-sum: task (pt, c8), 16 independent loads ------------------
    {
        int c8 = threadIdx.x & 15, pt = threadIdx.x >> 4;
        const unsigned short* base = xb + c8 * 8;
        float s[8] = {0, 0, 0, 0, 0, 0, 0, 0};
        #pragma unroll
        for (int t = 0; t < KNN; ++t) {
            int j = nbrs[pt][t];
            uint4 v = *(const uint4*)(base + (size_t)j * HID);
            s[0] += bflo(v.x); s[1] += bfhi(v.x);
            s[2] += bflo(v.y); s[3] += bfhi(v.y);
            s[4] += bflo(v.z); s[5] += bfhi(v.z);
            s[6] += bflo(v.w); s[7] += bfhi(v.w);
        }
        uint4 ov;
        ov.x = (unsigned)f2bf(s[0]) | ((unsigned)f2bf(s[1]) << 16);
        ov.y = (unsigned)f2bf(s[2]) | ((unsigned)f2bf(s[3]) << 16);
        ov.z = (unsigned)f2bf(s[4]) | ((unsigned)f2bf(s[5]) << 16);
        ov.w = (unsigned)f2bf(s[6]) | ((unsigned)f2bf(s[7]) << 16);
        *(uint4*)&aggs[pt][c8 * 8] = ov;
    }
    __syncthreads();

    // ---- MFMA: wave tile 16 pts x 32 h ------------------------------------
    const int wv = threadIdx.x >> 6;              // 0..15
    const int lane = threadIdx.x & 63;
    const int ptw = (wv & 3) * 16;                // 0/16/32/48
    const int h0w = (wv >> 2) * 32;               // 0/32/64/96
    const int row = lane & 15;
    const int quad = lane >> 4;

    f32x4 acc[2];
    acc[0] = (f32x4){0, 0, 0, 0};
    acc[1] = (f32x4){0, 0, 0, 0};

    // agg @ Wr^T
    #pragma unroll
    for (int kc = 0; kc < 4; ++kc) {
        bf16x8 a0 = *(const bf16x8*)&aggs[ptw + row][quad * 8 + kc * 32];
        #pragma unroll
        for (int n = 0; n < 2; ++n) {
            bf16x8 bb = *(const bf16x8*)&Wr[(size_t)(h0w + n * 16 + row) * HID
                                            + quad * 8 + kc * 32];
            acc[n] = __builtin_amdgcn_mfma_f32_16x16x32_bf16(a0, bb, acc[n], 0, 0, 0);
        }
    }
    // x @ Ws^T
    const unsigned short* xr0 = x + (size_t)(p0 + ptw + row) * HID + quad * 8;
    #pragma unroll
    for (int kc = 0; kc < 4; ++kc) {
        bf16x8 a0 = *(const bf16x8*)(xr0 + kc * 32);
        #pragma unroll
        for (int n = 0; n < 2; ++n) {
            bf16x8 bb = *(const bf16x8*)&Ws[(size_t)(h0w + n * 16 + row) * HID
                                            + quad * 8 + kc * 32];
            acc[n] = __builtin_amdgcn_mfma_f32_16x16x32_bf16(a0, bb, acc[n], 0, 0, 0);
        }
    }

    // ---- epilogue ---------------------------------------------------------
    #pragma unroll
    for (int n = 0; n < 2; ++n) {
        float bh = bias[h0w + n * 16 + row];
        #pragma unroll
        for (int r = 0; r < 4; ++r) {
            int pp = p0 + ptw + quad * 4 + r;
            float vv = acc[n][r] + bh;
            if (RELU) vv = fmaxf(vv, 0.f);
            if (OUT_BF16)
                ((unsigned short*)outv)[(size_t)pp * HID + h0w + n * 16 + row] = f2bf(vv);
            else
                ((float*)outv)[(size_t)pp * HID + h0w + n * 16 + row] = vv;
        }
    }
}

// ---------------------------------------------------------------------------
extern "C" void kernel_launch(void* const* d_in, const int* in_sizes, int n_in,
                              void* d_out, int out_size, void* d_ws, size_t ws_size,
                              hipStream_t stream)
{
    const float* pc  = (const float*)d_in[0];
    const float* W1r = (const float*)d_in[1];
    const float* b1  = (const float*)d_in[2];
    const float* W1s = (const float*)d_in[3];
    const float* W2r = (const float*)d_in[4];
    const float* b2  = (const float*)d_in[5];
    const float* W2s = (const float*)d_in[6];
    const float* W3r = (const float*)d_in[7];
    const float* b3  = (const float*)d_in[8];
    const float* W3s = (const float*)d_in[9];
    float* out = (float*)d_out;

    char* ws = (char*)d_ws;
    const size_t MB = 1024 * 1024;
    int*            nbr = (int*)ws;                             // 2 MB
    unsigned short* x1  = (unsigned short*)(ws + 2 * MB);       // 8.39 MB
    unsigned short* x2  = (unsigned short*)(ws + 2 * MB + 8388608);
    unsigned short* wbf = (unsigned short*)(ws + 2 * MB + 2 * 8388608);
    unsigned short* w2r = wbf;
    unsigned short* w2s = wbf + 16384;
    unsigned short* w3r = wbf + 32768;
    unsigned short* w3s = wbf + 49152;

    const int NPOINTS = BATCH * NPTS;                           // 32768

    wcvt_kernel<<<256, 256, 0, stream>>>(W2r, W2s, W3r, W3s, wbf);
    knn_kernel<<<NPOINTS / RPB, 512, 0, stream>>>(pc, nbr, W1r, b1, W1s, x1);

    conv_fused<true, true><<<NPOINTS / 64, 1024, 0, stream>>>(
        x1, nbr, w2r, w2s, b2, x2);
    conv_fused<false, false><<<NPOINTS / 64, 1024, 0, stream>>>(
        x2, nbr, w3r, w3s, b3, out);
}

// Round 10
// 174.435 us; speedup vs baseline: 1.1283x; 1.0611x over previous
//
#include <hip/hip_runtime.h>
#include <math.h>

#define NPTS 2048
#define BATCH 16
#define KNN 16
#define HID 128
#define RPB 8          // rows (queries) per block = waves per block
#define CAP 128        // compacted-candidate capacity per wave

typedef __attribute__((ext_vector_type(8))) short bf16x8;
typedef __attribute__((ext_vector_type(4))) float f32x4;

__device__ inline unsigned short f2bf(float f) {    // RNE f32 -> bf16 bits
    unsigned u = __float_as_uint(f);
    return (unsigned short)((u + 0x7FFFu + ((u >> 16) & 1u)) >> 16);
}
__device__ inline float bflo(unsigned v) { return __uint_as_float(v << 16); }
__device__ inline float bfhi(unsigned v) { return __uint_as_float(v & 0xFFFF0000u); }

// ---------------------------------------------------------------------------
// kNN + fused layer 1. One wave per query row. (R7/R9-proven, unchanged.)
// ---------------------------------------------------------------------------
__global__ __launch_bounds__(512) void knn_kernel(
    const float* __restrict__ pc, int* __restrict__ nbr,
    const float* __restrict__ W1r, const float* __restrict__ b1,
    const float* __restrict__ W1s, unsigned short* __restrict__ x1)
{
    __shared__ __align__(16) float4 pts[NPTS];        // x,y,z,|p|^2  (32 KB)
    __shared__ unsigned ckey[RPB][CAP];               // 4 KB
    __shared__ unsigned cidx[RPB][CAP];               // 4 KB

    const int b = blockIdx.x >> 8;                    // 256 blocks per batch
    const int rblk = blockIdx.x & 255;
    const float* p = pc + (size_t)b * NPTS * 3;

    for (int t = threadIdx.x; t < NPTS; t += 512) {
        float x = p[t * 3 + 0], y = p[t * 3 + 1], z = p[t * 3 + 2];
        pts[t] = make_float4(x, y, z, x * x + y * y + z * z);
    }
    __syncthreads();

    const int w = threadIdx.x >> 6;
    const int lane = threadIdx.x & 63;
    const int i = rblk * RPB + w;                     // query row in batch
    const float4 pi = pts[i];
    const float piw16 = pi.w + 16.0f;

    unsigned key[32];
    unsigned km = 0xFFFFFFFFu;
    #pragma unroll
    for (int t = 0; t < 32; ++t) {
        float4 c = pts[t * 64 + lane];
        float dot = fmaf(pi.x, c.x, fmaf(pi.y, c.y, pi.z * c.z));
        float d2 = fmaf(-2.0f, dot, piw16 + c.w);
        key[t] = __float_as_uint(d2);
        km = min(km, key[t]);
    }

    unsigned v = km;
    #pragma unroll
    for (int k = 2; k <= 64; k <<= 1) {
        #pragma unroll
        for (int j = k >> 1; j > 0; j >>= 1) {
            unsigned o = (unsigned)__shfl_xor((int)v, j, 64);
            bool sel = ((lane & k) == 0) == ((lane & j) == 0);
            v = sel ? min(v, o) : max(v, o);
        }
    }
    const unsigned T0 = (unsigned)__shfl((int)v, 15, 64);
    // >=16 candidates have key <= T0, and T0 >= true 16th-smallest
    // => {key <= T0} is a superset of the top-16.

    unsigned base = 0;
    #pragma unroll 1
    for (int t = 0; t < 32; ++t) {
        bool pred = key[t] <= T0;
        unsigned long long mask = __ballot(pred);
        if (mask) {
            unsigned prefix = __builtin_amdgcn_mbcnt_hi(
                (unsigned)(mask >> 32),
                __builtin_amdgcn_mbcnt_lo((unsigned)mask, 0));
            unsigned pos = base + prefix;
            if (pred && pos < CAP) {
                ckey[w][pos] = key[t];
                cidx[w][pos] = (unsigned)(t * 64 + lane);
            }
            base += (unsigned)__popcll(mask);
        }
    }
    __threadfence_block();
    const int m = (int)base;

    int* out = nbr + ((size_t)b * NPTS + i) * KNN;
    float ax = 0.f, ay = 0.f, az = 0.f;               // fused position sum

    if (m <= CAP) {
        unsigned k0 = (lane < m) ? ckey[w][lane] : 0xFFFFFFFFu;
        unsigned k1 = (lane + 64 < m) ? ckey[w][lane + 64] : 0xFFFFFFFFu;
        int r0 = 0, r1 = 0;
        if (m <= 64) {
            #pragma unroll 1
            for (int jj = 0; jj < m; ++jj) {
                unsigned kj = ckey[w][jj];
                r0 += (kj < k0) || (kj == k0 && jj < lane);
            }
        } else {
            #pragma unroll 1
            for (int jj = 0; jj < m; ++jj) {
                unsigned kj = ckey[w][jj];
                r0 += (kj < k0) || (kj == k0 && jj < lane);
                r1 += (kj < k1) || (kj == k1 && jj < lane + 64);
            }
        }
        if (lane < m && r0 < KNN) {
            unsigned j = cidx[w][lane];
            out[r0] = (int)j;
            float4 q = pts[j]; ax += q.x; ay += q.y; az += q.z;
        }
        if (m > 64 && lane + 64 < m && r1 < KNN) {
            unsigned j = cidx[w][lane + 64];
            out[r1] = (int)j;
            float4 q = pts[j]; ax += q.x; ay += q.y; az += q.z;
        }
    } else {
        // exact fallback (never taken w/ random data; correctness only)
        unsigned T = 0;
        #pragma unroll 1
        for (int bit = 31; bit >= 0; --bit) {
            unsigned trial = T | (1u << bit);
            int cnt = 0;
            #pragma unroll
            for (int t = 0; t < 32; ++t) cnt += (key[t] < trial);
            #pragma unroll
            for (int off = 32; off; off >>= 1)
                cnt += __shfl_xor(cnt, off, 64);
            if (cnt < KNN) T = trial;
        }
        unsigned bs = 0;
        #pragma unroll 1
        for (int t = 0; t < 32; ++t) {
            bool p1 = key[t] < T;
            unsigned long long mask = __ballot(p1);
            if (mask) {
                unsigned prefix = __builtin_amdgcn_mbcnt_hi(
                    (unsigned)(mask >> 32),
                    __builtin_amdgcn_mbcnt_lo((unsigned)mask, 0));
                if (p1) {
                    out[bs + prefix] = t * 64 + lane;
                    float4 q = pts[t * 64 + lane];
                    ax += q.x; ay += q.y; az += q.z;
                }
                bs += (unsigned)__popcll(mask);
            }
        }
        #pragma unroll 1
        for (int t = 0; t < 32 && bs < KNN; ++t) {
            bool p2 = key[t] == T;
            unsigned long long mask = __ballot(p2);
            if (mask) {
                unsigned prefix = __builtin_amdgcn_mbcnt_hi(
                    (unsigned)(mask >> 32),
                    __builtin_amdgcn_mbcnt_lo((unsigned)mask, 0));
                unsigned pos = bs + prefix;
                if (p2 && pos < KNN) {
                    out[pos] = t * 64 + lane;
                    float4 q = pts[t * 64 + lane];
                    ax += q.x; ay += q.y; az += q.z;
                }
                bs += (unsigned)__popcll(mask);
            }
        }
    }

    #pragma unroll
    for (int off = 32; off; off >>= 1) {
        ax += __shfl_xor(ax, off, 64);
        ay += __shfl_xor(ay, off, 64);
        az += __shfl_xor(az, off, 64);
    }

    unsigned short* xrow = x1 + ((size_t)b * NPTS + i) * HID;
    #pragma unroll
    for (int hh = 0; hh < 2; ++hh) {
        int h = lane + hh * 64;
        float acc = b1[h];
        acc += W1r[h * 3 + 0] * ax + W1r[h * 3 + 1] * ay + W1r[h * 3 + 2] * az;
        acc += W1s[h * 3 + 0] * pi.x + W1s[h * 3 + 1] * pi.y + W1s[h * 3 + 2] * pi.z;
        xrow[h] = f2bf(fmaxf(acc, 0.f));
    }
}

// ---------------------------------------------------------------------------
// Weight conversion: 4 x [128x128] f32 -> bf16.
// ---------------------------------------------------------------------------
__global__ __launch_bounds__(256) void wcvt_kernel(
    const float* __restrict__ a, const float* __restrict__ b,
    const float* __restrict__ c, const float* __restrict__ d,
    unsigned short* __restrict__ out)
{
    int g = blockIdx.x * 256 + threadIdx.x;       // < 65536
    int m = g >> 14;
    const float* s = (m == 0) ? a : (m == 1) ? b : (m == 2) ? c : d;
    out[g] = f2bf(s[g & 16383]);
}

// ---------------------------------------------------------------------------
// Fused gather + GraphConv via bf16 MFMA, v3: coalesced epilogue.
// R7 structure (512 thr, 8 waves, 64 pts x 128 h, wave tile 32x32) but the
// output tile is staged in LDS (union with the agg buffer — agg reads are
// done before the epilogue barrier) and stored as row-major 16B chunks.
// Rationale: the former epilogue issued 4.2M scattered 2B/4B stores per
// conv (MFMA D-layout scatters rows across lanes) — suspected dominant
// cost; every conv variant since R5 shared it and none improved.
// ---------------------------------------------------------------------------
template <bool RELU, bool OUT_BF16>
__global__ __launch_bounds__(512) void conv_fused(
    const unsigned short* __restrict__ x, const int* __restrict__ nbr,
    const unsigned short* __restrict__ Wr, const unsigned short* __restrict__ Ws,
    const float* __restrict__ bias, void* __restrict__ outv)
{
    // union: bf16 agg tile [64][136] (17.4 KB) / f32 out tile [64][132] (33.8 KB)
    __shared__ __align__(16) char smem[64 * 132 * 4];
    __shared__ int nbrs[64][17];                             // 4.4 KB
    unsigned short (*aggs)[136] = (unsigned short (*)[136])smem;
    float (*outs)[132] = (float (*)[132])smem;

    const int p0 = blockIdx.x * 64;                          // global point base
    const int bt = p0 >> 11;                                 // batch
    const unsigned short* xb = x + ((size_t)bt << 11) * HID; // batch-local rows

    // ---- stage nbr into LDS (coalesced) -----------------------------------
    for (int e = threadIdx.x; e < 64 * KNN; e += 512)
        nbrs[e >> 4][e & 15] = nbr[(size_t)p0 * KNN + e];
    __syncthreads();

    // ---- gather-sum -> bf16 agg tile (wave = 4 pts x 16 chunks) -----------
    #pragma unroll
    for (int it = 0; it < 2; ++it) {
        int task = it * 512 + threadIdx.x;        // 0..1023
        int c8 = task & 15, pt = task >> 4;       // pt 0..63
        const unsigned short* base = xb + c8 * 8;
        float s[8] = {0, 0, 0, 0, 0, 0, 0, 0};
        #pragma unroll
        for (int t = 0; t < KNN; ++t) {
            int j = nbrs[pt][t];
            uint4 v = *(const uint4*)(base + (size_t)j * HID);
            s[0] += bflo(v.x); s[1] += bfhi(v.x);
            s[2] += bflo(v.y); s[3] += bfhi(v.y);
            s[4] += bflo(v.z); s[5] += bfhi(v.z);
            s[6] += bflo(v.w); s[7] += bfhi(v.w);
        }
        uint4 ov;
        ov.x = (unsigned)f2bf(s[0]) | ((unsigned)f2bf(s[1]) << 16);
        ov.y = (unsigned)f2bf(s[2]) | ((unsigned)f2bf(s[3]) << 16);
        ov.z = (unsigned)f2bf(s[4]) | ((unsigned)f2bf(s[5]) << 16);
        ov.w = (unsigned)f2bf(s[6]) | ((unsigned)f2bf(s[7]) << 16);
        *(uint4*)&aggs[pt][c8 * 8] = ov;
    }
    __syncthreads();

    // ---- MFMA: wave tile 32 pts x 32 h ------------------------------------
    const int wv = threadIdx.x >> 6;
    const int lane = threadIdx.x & 63;
    const int ptw = (wv & 1) * 32;                // 0 / 32
    const int h0w = (wv >> 1) * 32;               // 0 / 32 / 64 / 96
    const int row = lane & 15;
    const int quad = lane >> 4;

    f32x4 acc[2][2];
    #pragma unroll
    for (int i = 0; i < 2; ++i)
        #pragma unroll
        for (int n = 0; n < 2; ++n) acc[i][n] = (f32x4){0, 0, 0, 0};

    #pragma unroll
    for (int kc = 0; kc < 4; ++kc) {
        bf16x8 a0 = *(const bf16x8*)&aggs[ptw + row][quad * 8 + kc * 32];
        bf16x8 a1 = *(const bf16x8*)&aggs[ptw + 16 + row][quad * 8 + kc * 32];
        #pragma unroll
        for (int n = 0; n < 2; ++n) {
            bf16x8 bb = *(const bf16x8*)&Wr[(size_t)(h0w + n * 16 + row) * HID
                                            + quad * 8 + kc * 32];
            acc[0][n] = __builtin_amdgcn_mfma_f32_16x16x32_bf16(a0, bb, acc[0][n], 0, 0, 0);
            acc[1][n] = __builtin_amdgcn_mfma_f32_16x16x32_bf16(a1, bb, acc[1][n], 0, 0, 0);
        }
    }
    const unsigned short* xr0 = x + (size_t)(p0 + ptw + row) * HID + quad * 8;
    const unsigned short* xr1 = xr0 + 16 * HID;
    #pragma unroll
    for (int kc = 0; kc < 4; ++kc) {
        bf16x8 a0 = *(const bf16x8*)(xr0 + kc * 32);
        bf16x8 a1 = *(const bf16x8*)(xr1 + kc * 32);
        #pragma unroll
        for (int n = 0; n < 2; ++n) {
            bf16x8 bb = *(const bf16x8*)&Ws[(size_t)(h0w + n * 16 + row) * HID
                                            + quad * 8 + kc * 32];
            acc[0][n] = __builtin_amdgcn_mfma_f32_16x16x32_bf16(a0, bb, acc[0][n], 0, 0, 0);
            acc[1][n] = __builtin_amdgcn_mfma_f32_16x16x32_bf16(a1, bb, acc[1][n], 0, 0, 0);
        }
    }

    // ---- epilogue: bias/relu in regs -> LDS tile -> coalesced stores ------
    __syncthreads();                              // all agg reads complete
    #pragma unroll
    for (int n = 0; n < 2; ++n) {
        float bh = bias[h0w + n * 16 + row];
        #pragma unroll
        for (int i = 0; i < 2; ++i) {
            #pragma unroll
            for (int r = 0; r < 4; ++r) {
                int pt = ptw + i * 16 + quad * 4 + r;     // 0..63 in tile
                int hh = h0w + n * 16 + row;              // 0..127
                float vv = acc[i][n][r] + bh;
                if (RELU) vv = fmaxf(vv, 0.f);
                if (OUT_BF16) aggs[pt][hh] = f2bf(vv);
                else          outs[pt][hh] = vv;
            }
        }
    }
    __syncthreads();

    if (OUT_BF16) {
        unsigned short* o = (unsigned short*)outv;
        #pragma unroll
        for (int q = 0; q < 2; ++q) {
            int task = q * 512 + threadIdx.x;     // 0..1023 = 64 rows x 16 chunks
            int rr = task >> 4, ch = task & 15;
            *(uint4*)(o + (size_t)(p0 + rr) * HID + ch * 8) =
                *(const uint4*)&aggs[rr][ch * 8];
        }
    } else {
        float* o = (float*)outv;
        #pragma unroll
        for (int q = 0; q < 4; ++q) {
            int task = q * 512 + threadIdx.x;     // 0..2047 = 64 rows x 32 chunks
            int rr = task >> 5, ch = task & 31;
            *(float4*)(o + (size_t)(p0 + rr) * HID + ch * 4) =
                *(const float4*)&outs[rr][ch * 4];
        }
    }
}

// ---------------------------------------------------------------------------
extern "C" void kernel_launch(void* const* d_in, const int* in_sizes, int n_in,
                              void* d_out, int out_size, void* d_ws, size_t ws_size,
                              hipStream_t stream)
{
    const float* pc  = (const float*)d_in[0];
    const float* W1r = (const float*)d_in[1];
    const float* b1  = (const float*)d_in[2];
    const float* W1s = (const float*)d_in[3];
    const float* W2r = (const float*)d_in[4];
    const float* b2  = (const float*)d_in[5];
    const float* W2s = (const float*)d_in[6];
    const float* W3r = (const float*)d_in[7];
    const float* b3  = (const float*)d_in[8];
    const float* W3s = (const float*)d_in[9];
    float* out = (float*)d_out;

    char* ws = (char*)d_ws;
    const size_t MB = 1024 * 1024;
    int*            nbr = (int*)ws;                             // 2 MB
    unsigned short* x1  = (unsigned short*)(ws + 2 * MB);       // 8.39 MB
    unsigned short* x2  = (unsigned short*)(ws + 2 * MB + 8388608);
    unsigned short* wbf = (unsigned short*)(ws + 2 * MB + 2 * 8388608);
    unsigned short* w2r = wbf;
    unsigned short* w2s = wbf + 16384;
    unsigned short* w3r = wbf + 32768;
    unsigned short* w3s = wbf + 49152;

    const int NPOINTS = BATCH * NPTS;                           // 32768

    wcvt_kernel<<<256, 256, 0, stream>>>(W2r, W2s, W3r, W3s, wbf);
    knn_kernel<<<NPOINTS / RPB, 512, 0, stream>>>(pc, nbr, W1r, b1, W1s, x1);

    conv_fused<true, true><<<NPOINTS / 64, 512, 0, stream>>>(
        x1, nbr, w2r, w2s, b2, x2);
    conv_fused<false, false><<<NPOINTS / 64, 512, 0, stream>>>(
        x2, nbr, w3r, w3s, b3, out);
}